// Round 1
// 232.818 us; speedup vs baseline: 1.0801x; 1.0801x over previous
//
#include <hip/hip_runtime.h>
#include <hip/hip_bf16.h>

typedef short bf16x8 __attribute__((ext_vector_type(8)));
typedef _Float16 f16;
typedef f16 f16x8 __attribute__((ext_vector_type(8)));
typedef float f32x4 __attribute__((ext_vector_type(4)));
typedef unsigned short u16;
typedef u16 u16x8 __attribute__((ext_vector_type(8)));
typedef unsigned int u32;
typedef u32 u32x2 __attribute__((ext_vector_type(2)));

#define B_  2
#define L_  4096
#define F_  512
#define H_  8
#define D_  64
#define M_  8192       // B_*L_
#define NSPL 2         // flash split-K factor
#define KHALF (L_ / NSPL)

#define LOG2E 1.442695041f

__device__ inline u16 f2bf(float f) {
    union { float f; unsigned u; } v; v.f = f;
    unsigned r = v.u + 0x7fff + ((v.u >> 16) & 1);  // RNE
    return (u16)(r >> 16);
}
__device__ inline u16 f2h(float f) {
    union { f16 h; u16 u; } v; v.h = (f16)f;  // RNE hw cvt
    return v.u;
}
__device__ inline float h2f(u16 u) {
    union { u16 u; f16 h; } v; v.u = u;
    return (float)v.h;
}

// ---------------------------------------------------------------------------
// Fused weight transpose: W [512 k][512 n] fp32 -> Wt [512 n][512 k] fp16.
// ---------------------------------------------------------------------------
__global__ __launch_bounds__(256) void wt_kernel(
    const float* __restrict__ Wq, const float* __restrict__ Wk,
    const float* __restrict__ Wv, const float* __restrict__ Wo,
    u16* __restrict__ Tq, u16* __restrict__ Tk,
    u16* __restrict__ Tv, u16* __restrict__ To) {
    __shared__ float t[32][33];
    const int z = blockIdx.z;
    const float* in = (z == 0) ? Wq : (z == 1) ? Wk : (z == 2) ? Wv : Wo;
    u16* out = (z == 0) ? Tq : (z == 1) ? Tk : (z == 2) ? Tv : To;
    int k0 = blockIdx.y * 32, n0 = blockIdx.x * 32;
    int c = threadIdx.x & 31, r8 = threadIdx.x >> 5;
#pragma unroll
    for (int i = 0; i < 4; ++i) {
        int r = r8 * 4 + i;
        t[r][c] = in[(size_t)(k0 + r) * F_ + n0 + c];
    }
    __syncthreads();
#pragma unroll
    for (int i = 0; i < 4; ++i) {
        int r = r8 * 4 + i;
        out[(size_t)(n0 + r) * F_ + k0 + c] = f2h(t[c][r]);
    }
}

// ---------------------------------------------------------------------------
// Fused projection kernel, 128x64 tile, register prefetch (loads issued
// AFTER the barrier pair so no barrier drains a fresh vmcnt).
// z=0: Q = Xq*Wq (scaled log2e) -> [B,H,L,D] fp16.
// z=1: K -> [B,H,L,D] fp16;  V -> [B,H,D,L] bf16 transposed.
// ---------------------------------------------------------------------------
__global__ __launch_bounds__(256, 3) void proj_kernel(
    const float* __restrict__ Xq, const float* __restrict__ Xkv,
    const u16* __restrict__ Wqt, const u16* __restrict__ Wkt,
    const u16* __restrict__ Wvt,
    u16* __restrict__ Qw, u16* __restrict__ Kw, u16* __restrict__ Vw) {
    __shared__ u16 Ah[128][72];
    __shared__ u16 B1[64][72];
    __shared__ u16 B2[64][72];
    const int tid = threadIdx.x;
    const int w = tid >> 6, lane = tid & 63, lx = lane & 15, quad = lane >> 4;
    const int m0 = blockIdx.y * 128, n0 = blockIdx.x * 64;
    const bool isKV = (blockIdx.z == 1);
    const float* A = isKV ? Xkv : Xq;
    const u16* W1 = isKV ? Wkt : Wqt;

    float4 apre[8];
    u16x8 b1p[2], b2p[2];

    auto load_ab = [&](int k0) {
#pragma unroll
        for (int it = 0; it < 4; ++it) {
            int slot = tid + it * 256, r = slot >> 3, g = (slot & 7) * 8;
            apre[2 * it]     = *(const float4*)(A + (size_t)(m0 + r) * F_ + k0 + g);
            apre[2 * it + 1] = *(const float4*)(A + (size_t)(m0 + r) * F_ + k0 + g + 4);
        }
#pragma unroll
        for (int it = 0; it < 2; ++it) {
            int slot = tid + it * 256, r = slot >> 3, g = (slot & 7) * 8;
            b1p[it] = *(const u16x8*)(W1 + (size_t)(n0 + r) * F_ + k0 + g);
            if (isKV)
                b2p[it] = *(const u16x8*)(Wvt + (size_t)(n0 + r) * F_ + k0 + g);
        }
    };
    auto write_ab = [&]() {
#pragma unroll
        for (int it = 0; it < 4; ++it) {
            int slot = tid + it * 256, r = slot >> 3, g = (slot & 7) * 8;
            float4 f0 = apre[2 * it], f1 = apre[2 * it + 1];
            u16 th[8] = {f2h(f0.x), f2h(f0.y), f2h(f0.z), f2h(f0.w),
                         f2h(f1.x), f2h(f1.y), f2h(f1.z), f2h(f1.w)};
            *(u16x8*)&Ah[r][g] = *(u16x8*)th;
        }
#pragma unroll
        for (int it = 0; it < 2; ++it) {
            int slot = tid + it * 256, r = slot >> 3, g = (slot & 7) * 8;
            *(u16x8*)&B1[r][g] = b1p[it];
            if (isKV) *(u16x8*)&B2[r][g] = b2p[it];
        }
    };

    f32x4 acc1[2][4] = {}, acc2[2][4] = {};

    load_ab(0);
    write_ab();
    __syncthreads();
    load_ab(64);   // in flight during first compute

    for (int k0 = 0; k0 < F_; k0 += 64) {
#pragma unroll
        for (int ks = 0; ks < 2; ++ks) {
            f16x8 af[2];
#pragma unroll
            for (int mf = 0; mf < 2; ++mf)
                af[mf] = *(const f16x8*)&Ah[w * 32 + mf * 16 + lx][ks * 32 + quad * 8];
#pragma unroll
            for (int nt = 0; nt < 4; ++nt) {
                f16x8 b1 = *(const f16x8*)&B1[nt * 16 + lx][ks * 32 + quad * 8];
#pragma unroll
                for (int mf = 0; mf < 2; ++mf)
                    acc1[mf][nt] = __builtin_amdgcn_mfma_f32_16x16x32_f16(af[mf], b1, acc1[mf][nt], 0, 0, 0);
                if (isKV) {
                    f16x8 b2 = *(const f16x8*)&B2[nt * 16 + lx][ks * 32 + quad * 8];
#pragma unroll
                    for (int mf = 0; mf < 2; ++mf)
                        acc2[mf][nt] = __builtin_amdgcn_mfma_f32_16x16x32_f16(af[mf], b2, acc2[mf][nt], 0, 0, 0);
                }
            }
        }
        if (k0 < F_ - 64) {
            __syncthreads();   // loads for k0+64 landed during this compute
            write_ab();
            __syncthreads();
            if (k0 < F_ - 128) load_ab(k0 + 128);  // issued AFTER barriers
        }
    }

    const int h = n0 >> 6;
    const float scl = isKV ? 1.0f : LOG2E;
    u16* C1 = isKV ? Kw : Qw;
#pragma unroll
    for (int mf = 0; mf < 2; ++mf)
#pragma unroll
        for (int nt = 0; nt < 4; ++nt)
#pragma unroll
            for (int i = 0; i < 4; ++i) {
                int m = m0 + w * 32 + mf * 16 + quad * 4 + i;
                int b = m >> 12, l = m & 4095;
                int d = nt * 16 + lx;
                C1[((size_t)(b * H_ + h) * L_ + l) * D_ + d] = f2h(acc1[mf][nt][i] * scl);
            }
    if (isKV) {
        __syncthreads();
#pragma unroll
        for (int mf = 0; mf < 2; ++mf)
#pragma unroll
            for (int nt = 0; nt < 4; ++nt)
#pragma unroll
                for (int i = 0; i < 4; ++i)
                    Ah[w * 32 + mf * 16 + quad * 4 + i][nt * 16 + lx] = f2bf(acc2[mf][nt][i]);
        __syncthreads();
        int d = tid >> 2, seg = (tid & 3) * 32;
        int b = m0 >> 12;
        u16 tmp[32];
#pragma unroll
        for (int j = 0; j < 32; ++j) tmp[j] = Ah[seg + j][d];
        size_t base = ((size_t)(b * H_ + h) * D_ + d) * L_ + (m0 & 4095) + seg;
#pragma unroll
        for (int c = 0; c < 4; ++c)
            *(u16x8*)(Vw + base + c * 8) = *(u16x8*)&tmp[c * 8];
    }
}

// ---------------------------------------------------------------------------
// Out-projection GEMM, 128x64 tile: A fp16 x Wt fp16 -> C fp32.
// ---------------------------------------------------------------------------
__global__ __launch_bounds__(256) void out_gemm(const u16* __restrict__ A16,
                                                const u16* __restrict__ Wt,
                                                float* __restrict__ Cf) {
    __shared__ u16 As[128][72];
    __shared__ u16 Bs[64][72];
    const int tid = threadIdx.x;
    const int w = tid >> 6, lane = tid & 63, lx = lane & 15, quad = lane >> 4;
    const int m0 = blockIdx.y * 128, n0 = blockIdx.x * 64;

    u16x8 a16p[4];
    u16x8 bp[2];

    auto load_ab = [&](int k0) {
#pragma unroll
        for (int it = 0; it < 4; ++it) {
            int slot = tid + it * 256, r = slot >> 3, g = (slot & 7) * 8;
            a16p[it] = *(const u16x8*)(A16 + (size_t)(m0 + r) * F_ + k0 + g);
        }
#pragma unroll
        for (int it = 0; it < 2; ++it) {
            int slot = tid + it * 256, r = slot >> 3, g = (slot & 7) * 8;
            bp[it] = *(const u16x8*)(Wt + (size_t)(n0 + r) * F_ + k0 + g);
        }
    };
    auto write_ab = [&]() {
#pragma unroll
        for (int it = 0; it < 4; ++it) {
            int slot = tid + it * 256, r = slot >> 3, g = (slot & 7) * 8;
            *(u16x8*)&As[r][g] = a16p[it];
        }
#pragma unroll
        for (int it = 0; it < 2; ++it) {
            int slot = tid + it * 256, r = slot >> 3, g = (slot & 7) * 8;
            *(u16x8*)&Bs[r][g] = bp[it];
        }
    };

    f32x4 acc[2][4] = {};

    load_ab(0);
    write_ab();
    __syncthreads();
    load_ab(64);

    for (int k0 = 0; k0 < F_; k0 += 64) {
#pragma unroll
        for (int ks = 0; ks < 2; ++ks) {
            f16x8 af[2];
#pragma unroll
            for (int mf = 0; mf < 2; ++mf)
                af[mf] = *(const f16x8*)&As[w * 32 + mf * 16 + lx][ks * 32 + quad * 8];
#pragma unroll
            for (int nt = 0; nt < 4; ++nt) {
                f16x8 bf = *(const f16x8*)&Bs[nt * 16 + lx][ks * 32 + quad * 8];
#pragma unroll
                for (int mf = 0; mf < 2; ++mf)
                    acc[mf][nt] = __builtin_amdgcn_mfma_f32_16x16x32_f16(af[mf], bf, acc[mf][nt], 0, 0, 0);
            }
        }
        if (k0 < F_ - 64) {
            __syncthreads();
            write_ab();
            __syncthreads();
            if (k0 < F_ - 128) load_ab(k0 + 128);
        }
    }

#pragma unroll
    for (int mf = 0; mf < 2; ++mf)
#pragma unroll
        for (int nt = 0; nt < 4; ++nt)
#pragma unroll
            for (int i = 0; i < 4; ++i) {
                int m = m0 + w * 32 + mf * 16 + quad * 4 + i;
                int n = n0 + nt * 16 + lx;
                Cf[(size_t)m * F_ + n] = acc[mf][nt][i];
            }
}

// ---------------------------------------------------------------------------
// MFMA flash attention: BQ=128 (4 waves x 32q), split-K x2, Q in registers.
// Prefetch loads issued AFTER the barrier pair (no vmcnt drain at barriers).
// p = exp2(s) (Q pre-scaled log2e; constant bias cancels in normalization).
//
// THIS ROUND: P never touches LDS. After the swapped QK^T (S^T = K Q^T),
// lane (lx,quad) holds S^T[k=nt*16+quad*4+i][q=lx] — q is already
// lane-local; only the k distribution across quads mismatches the PV
// A-fragment (lane needs P[q=lx][k=ks*32+quad*8+j]). That permutation
// crosses only lane bits 4-5, so it is exactly two VALU swaps:
//   a=pack(i0,i1)@nt=2ks, b=pack(i0,i1)@nt=2ks+1
//   {a1,b1} = permlane32_swap(a,b)   -> a1=[a.q0,a.q1,b.q0,b.q1]
//   {T0,T2} = permlane16_swap(a1,b1) -> T0=[a.q0,a.q2,b.q0,b.q2]
//                                       T2=[a.q1,a.q3,b.q1,b.q3]
// (same with pack(i2,i3) giving T1,T3). This removes 8 b64 LDS writes +
// 4 b128 LDS reads per wave per kt and the Ps buffer (LDS 36864->18432 B).
// Writes On_s = O_s/l_s (fp16) and l_s; combined exactly in reduce_kernel.
// XCD swizzle: (x&7) -> 2 heads per XCD (K/V WS 2 MB < 4 MB L2/XCD).
// ---------------------------------------------------------------------------
__global__ __launch_bounds__(256, 4) void flash_mfma(
    const u16* __restrict__ Qg, const u16* __restrict__ Kg,
    const u16* __restrict__ Vtg, u16* __restrict__ On, float* __restrict__ Ls) {
    __shared__ u16 Ks[64][72];   // fp16
    __shared__ u16 Vs[64][72];   // bf16, V^T tile [d][kcol]

    const int tid = threadIdx.x;
    const int w = tid >> 6, lane = tid & 63, lx = lane & 15, quad = lane >> 4;

    // decode: 1024 = 8 xcd * (2 head * 2 split * 32 qtile)
    const int x = blockIdx.x;
    const int t = x >> 3;
    const int hh = t >> 6;
    const int s = (t >> 5) & 1;
    const int bh = (x & 7) * 2 + hh;
    const int q0 = (t & 31) * 128;

    const u16* Qp = Qg + ((size_t)bh * L_ + q0) * D_;
    const u16* Kp = Kg + (size_t)bh * L_ * D_ + (size_t)(s * KHALF) * D_;
    const u16* Vp = Vtg + (size_t)bh * D_ * L_ + s * KHALF;

    // Q fragments straight to registers (B-operand layout)
    f16x8 qreg[2][2];
#pragma unroll
    for (int qf = 0; qf < 2; ++qf)
#pragma unroll
        for (int ks = 0; ks < 2; ++ks)
            qreg[qf][ks] = *(const f16x8*)(Qp + (size_t)(w * 32 + qf * 16 + lx) * D_ +
                                           ks * 32 + quad * 8);

    u16x8 kp[2], vp[2];
    auto load_kv = [&](int kt) {
#pragma unroll
        for (int it = 0; it < 2; ++it) {
            int slot = tid + it * 256, r = slot >> 3, g = (slot & 7) * 8;
            kp[it] = *(const u16x8*)(Kp + (size_t)(kt * 64 + r) * D_ + g);
            vp[it] = *(const u16x8*)(Vp + (size_t)r * L_ + kt * 64 + g);
        }
    };
    auto write_kv = [&]() {
#pragma unroll
        for (int it = 0; it < 2; ++it) {
            int slot = tid + it * 256, r = slot >> 3, g = (slot & 7) * 8;
            *(u16x8*)&Ks[r][g] = kp[it];
            *(u16x8*)&Vs[r][g] = vp[it];
        }
    };

    const bf16x8 vone = {0x3F80, 0x3F80, 0x3F80, 0x3F80,
                         0x3F80, 0x3F80, 0x3F80, 0x3F80};  // bf16 1.0 x8
    f32x4 o[2][4] = {};
    f32x4 osum[2] = {};

    load_kv(0);
    write_kv();
    __syncthreads();
    load_kv(1);   // in flight during first compute

    const int NT = KHALF / 64;
    for (int kt = 0; kt < NT; ++kt) {
        // S^T = K Q^T : lane holds S^T[k = nt*16+quad*4+i][q = w*32+qf*16+lx]
        f32x4 sv[4][2] = {};
#pragma unroll
        for (int ks = 0; ks < 2; ++ks) {
#pragma unroll
            for (int nt = 0; nt < 4; ++nt) {
                f16x8 ak = *(const f16x8*)&Ks[nt * 16 + lx][ks * 32 + quad * 8];
#pragma unroll
                for (int qf = 0; qf < 2; ++qf)
                    sv[nt][qf] = __builtin_amdgcn_mfma_f32_16x16x32_f16(ak, qreg[qf][ks], sv[nt][qf], 0, 0, 0);
            }
        }

        // p = exp2(s); truncate-pack pairs to bf16 dwords, all in registers.
        // pu[nt][qf] = bf16(p_i0)|bf16(p_i1)<<16 ; pw = same for i2,i3.
        u32 pu[4][2], pw[4][2];
#pragma unroll
        for (int nt = 0; nt < 4; ++nt)
#pragma unroll
            for (int qf = 0; qf < 2; ++qf) {
                u32 ub[4];
#pragma unroll
                for (int i = 0; i < 4; ++i)
                    ub[i] = __float_as_uint(__builtin_amdgcn_exp2f(sv[nt][qf][i]));
                pu[nt][qf] = __builtin_amdgcn_perm(ub[1], ub[0], 0x07060302u);
                pw[nt][qf] = __builtin_amdgcn_perm(ub[3], ub[2], 0x07060302u);
            }

        // Build PV A-fragments in-register: cross-quad redistribution via
        // permlane32_swap + permlane16_swap (VALU — no LDS round-trip).
        bf16x8 ap[2][2];  // [ks][qf]
#pragma unroll
        for (int ks = 0; ks < 2; ++ks)
#pragma unroll
            for (int qf = 0; qf < 2; ++qf) {
                u32x2 r  = __builtin_amdgcn_permlane32_swap(pu[2 * ks][qf], pu[2 * ks + 1][qf], false, false);
                u32x2 r2 = __builtin_amdgcn_permlane16_swap(r[0], r[1], false, false);
                u32x2 t  = __builtin_amdgcn_permlane32_swap(pw[2 * ks][qf], pw[2 * ks + 1][qf], false, false);
                u32x2 t2 = __builtin_amdgcn_permlane16_swap(t[0], t[1], false, false);
                union { u32 d[4]; bf16x8 h; } cvt;
                cvt.d[0] = r2[0];  // k = quad*8 + {0,1}
                cvt.d[1] = t2[0];  // k = quad*8 + {2,3}
                cvt.d[2] = r2[1];  // k = quad*8 + {4,5}
                cvt.d[3] = t2[1];  // k = quad*8 + {6,7}
                ap[ks][qf] = cvt.h;
            }

        // O += P V and row-sums osum += P * ones
#pragma unroll
        for (int ks = 0; ks < 2; ++ks) {
#pragma unroll
            for (int qf = 0; qf < 2; ++qf)
                osum[qf] = __builtin_amdgcn_mfma_f32_16x16x32_bf16(ap[ks][qf], vone, osum[qf], 0, 0, 0);
#pragma unroll
            for (int nt = 0; nt < 4; ++nt) {
                bf16x8 bv = *(const bf16x8*)&Vs[nt * 16 + lx][ks * 32 + quad * 8];
#pragma unroll
                for (int qf = 0; qf < 2; ++qf)
                    o[qf][nt] = __builtin_amdgcn_mfma_f32_16x16x32_bf16(ap[ks][qf], bv, o[qf][nt], 0, 0, 0);
            }
        }

        if (kt < NT - 1) {
            __syncthreads();   // kt+1 loads landed during this compute
            write_kv();
            __syncthreads();
            if (kt < NT - 2) load_kv(kt + 2);  // issued AFTER barriers
        }
    }

    // write On = O/l (fp16, [B,L,H*D]) and l (f32)
    const int b = bh >> 3, h = bh & 7;
    u16* Op = On + (size_t)s * M_ * F_;
#pragma unroll
    for (int qf = 0; qf < 2; ++qf) {
        float linv[4];
#pragma unroll
        for (int i = 0; i < 4; ++i) linv[i] = 1.f / osum[qf][i];
#pragma unroll
        for (int nt = 0; nt < 4; ++nt)
#pragma unroll
            for (int i = 0; i < 4; ++i) {
                int l = q0 + w * 32 + qf * 16 + quad * 4 + i;
                Op[((size_t)b * L_ + l) * (H_ * D_) + h * D_ + nt * 16 + lx] =
                    f2h(o[qf][nt][i] * linv[i]);
            }
        if (lx == 0) {
            float* lp = Ls + ((size_t)s * (B_ * H_) + bh) * L_ +
                        q0 + w * 32 + qf * 16 + quad * 4;
#pragma unroll
            for (int i = 0; i < 4; ++i) lp[i] = osum[qf][i];
        }
    }
}

// ---------------------------------------------------------------------------
// Combine split-K partials: O = (l1*O1n + l2*O2n) / (l1+l2).
// ---------------------------------------------------------------------------
__global__ __launch_bounds__(256) void reduce_kernel(
    const u16* __restrict__ On, const float* __restrict__ Ls,
    u16* __restrict__ Ow) {
    int gid = blockIdx.x * 256 + threadIdx.x;  // u16x8 group, grid covers M_*F_/8
    size_t off = (size_t)gid * 8;
    int row = gid >> 3;                        // 64 elems per (b,l,h) row
    int b = row >> 15, rem = row & 32767;
    int l = rem >> 3, h = rem & 7;
    int lidx = ((b * H_ + h) << 12) + l;
    float l1 = Ls[lidx], l2 = Ls[B_ * H_ * L_ + lidx];
    float w1 = l1 / (l1 + l2), w2 = 1.f - w1;
    u16x8 a = *(const u16x8*)(On + off);
    u16x8 c = *(const u16x8*)(On + (size_t)M_ * F_ + off);
    u16 r[8];
#pragma unroll
    for (int j = 0; j < 8; ++j)
        r[j] = f2h(w1 * h2f(a[j]) + w2 * h2f(c[j]));
    *(u16x8*)(Ow + off) = *(u16x8*)r;
}

// ---------------------------------------------------------------------------
extern "C" void kernel_launch(void* const* d_in, const int* in_sizes, int n_in,
                              void* d_out, int out_size, void* d_ws, size_t ws_size,
                              hipStream_t stream)
{
    const float* Xq  = (const float*)d_in[0];
    const float* Xkv = (const float*)d_in[1];
    const float* Wq  = (const float*)d_in[2];
    const float* Wk  = (const float*)d_in[3];
    const float* Wv  = (const float*)d_in[4];
    const float* Wo  = (const float*)d_in[5];
    float* out = (float*)d_out;

    u16* ws  = (u16*)d_ws;
    const size_t MF = (size_t)M_ * F_;
    const size_t FF = (size_t)F_ * F_;
    u16* Wqt = ws;             // W^T 512x512 fp16 each
    u16* Wkt = Wqt + FF;
    u16* Wvt = Wkt + FF;
    u16* Wot = Wvt + FF;
    u16* Qw  = Wot + FF;       // [B,H,L,D] fp16, pre-scaled by log2e
    u16* Kw  = Qw + MF;        // [B,H,L,D] fp16
    u16* Vw  = Kw + MF;        // [B,H,D,L] bf16
    u16* On  = Vw + MF;        // 2 x [B,L,H*D] fp16 split partials
    float* Ls = (float*)(On + 2 * MF);  // 2 x [BH, L] f32
    u16* Ow  = Qw;             // reduced O aliases Qw (dead after flash)

    wt_kernel<<<dim3(16, 16, 4), 256, 0, stream>>>(Wq, Wk, Wv, Wo,
                                                   Wqt, Wkt, Wvt, Wot);

    proj_kernel<<<dim3(8, 64, 2), 256, 0, stream>>>(Xq, Xkv, Wqt, Wkt, Wvt,
                                                    Qw, Kw, Vw);

    flash_mfma<<<dim3(1024), 256, 0, stream>>>(Qw, Kw, Vw, On, Ls);

    reduce_kernel<<<dim3((int)(MF / 8 / 256)), 256, 0, stream>>>(On, Ls, Ow);

    out_gemm<<<dim3(8, 64), 256, 0, stream>>>(Ow, Wot, out);
}

// Round 2
// 215.916 us; speedup vs baseline: 1.1647x; 1.0783x over previous
//
#include <hip/hip_runtime.h>
#include <hip/hip_bf16.h>

typedef short bf16x8 __attribute__((ext_vector_type(8)));
typedef _Float16 f16;
typedef f16 f16x8 __attribute__((ext_vector_type(8)));
typedef float f32x4 __attribute__((ext_vector_type(4)));
typedef unsigned short u16;
typedef u16 u16x8 __attribute__((ext_vector_type(8)));
typedef unsigned int u32;
typedef u32 u32x2 __attribute__((ext_vector_type(2)));

#define B_  2
#define L_  4096
#define F_  512
#define H_  8
#define D_  64
#define M_  8192       // B_*L_
#define NSPL 2         // flash split-K factor
#define KHALF (L_ / NSPL)

#define LOG2E 1.442695041f

__device__ inline u16 f2bf(float f) {
    union { float f; unsigned u; } v; v.f = f;
    unsigned r = v.u + 0x7fff + ((v.u >> 16) & 1);  // RNE
    return (u16)(r >> 16);
}
__device__ inline u16 f2h(float f) {
    union { f16 h; u16 u; } v; v.h = (f16)f;  // RNE hw cvt
    return v.u;
}
__device__ inline float h2f(u16 u) {
    union { u16 u; f16 h; } v; v.u = u;
    return (float)v.h;
}

// ---------------------------------------------------------------------------
// Fused weight transpose: W [512 k][512 n] fp32 -> Wt [512 n][512 k] fp16.
// ---------------------------------------------------------------------------
__global__ __launch_bounds__(256) void wt_kernel(
    const float* __restrict__ Wq, const float* __restrict__ Wk,
    const float* __restrict__ Wv, const float* __restrict__ Wo,
    u16* __restrict__ Tq, u16* __restrict__ Tk,
    u16* __restrict__ Tv, u16* __restrict__ To) {
    __shared__ float t[32][33];
    const int z = blockIdx.z;
    const float* in = (z == 0) ? Wq : (z == 1) ? Wk : (z == 2) ? Wv : Wo;
    u16* out = (z == 0) ? Tq : (z == 1) ? Tk : (z == 2) ? Tv : To;
    int k0 = blockIdx.y * 32, n0 = blockIdx.x * 32;
    int c = threadIdx.x & 31, r8 = threadIdx.x >> 5;
#pragma unroll
    for (int i = 0; i < 4; ++i) {
        int r = r8 * 4 + i;
        t[r][c] = in[(size_t)(k0 + r) * F_ + n0 + c];
    }
    __syncthreads();
#pragma unroll
    for (int i = 0; i < 4; ++i) {
        int r = r8 * 4 + i;
        out[(size_t)(n0 + r) * F_ + k0 + c] = f2h(t[c][r]);
    }
}

// ---------------------------------------------------------------------------
// Fused projection kernel, 128x64 tile, register prefetch (loads issued
// AFTER the barrier pair so no barrier drains a fresh vmcnt).
// z=0: Q = Xq*Wq (scaled log2e) -> [B,H,L,D] fp16.
// z=1: K -> [B,H,L,D] fp16;  V -> [B,H,D,L] bf16 transposed.
// ---------------------------------------------------------------------------
__global__ __launch_bounds__(256, 3) void proj_kernel(
    const float* __restrict__ Xq, const float* __restrict__ Xkv,
    const u16* __restrict__ Wqt, const u16* __restrict__ Wkt,
    const u16* __restrict__ Wvt,
    u16* __restrict__ Qw, u16* __restrict__ Kw, u16* __restrict__ Vw) {
    __shared__ u16 Ah[128][72];
    __shared__ u16 B1[64][72];
    __shared__ u16 B2[64][72];
    const int tid = threadIdx.x;
    const int w = tid >> 6, lane = tid & 63, lx = lane & 15, quad = lane >> 4;
    const int m0 = blockIdx.y * 128, n0 = blockIdx.x * 64;
    const bool isKV = (blockIdx.z == 1);
    const float* A = isKV ? Xkv : Xq;
    const u16* W1 = isKV ? Wkt : Wqt;

    float4 apre[8];
    u16x8 b1p[2], b2p[2];

    auto load_ab = [&](int k0) {
#pragma unroll
        for (int it = 0; it < 4; ++it) {
            int slot = tid + it * 256, r = slot >> 3, g = (slot & 7) * 8;
            apre[2 * it]     = *(const float4*)(A + (size_t)(m0 + r) * F_ + k0 + g);
            apre[2 * it + 1] = *(const float4*)(A + (size_t)(m0 + r) * F_ + k0 + g + 4);
        }
#pragma unroll
        for (int it = 0; it < 2; ++it) {
            int slot = tid + it * 256, r = slot >> 3, g = (slot & 7) * 8;
            b1p[it] = *(const u16x8*)(W1 + (size_t)(n0 + r) * F_ + k0 + g);
            if (isKV)
                b2p[it] = *(const u16x8*)(Wvt + (size_t)(n0 + r) * F_ + k0 + g);
        }
    };
    auto write_ab = [&]() {
#pragma unroll
        for (int it = 0; it < 4; ++it) {
            int slot = tid + it * 256, r = slot >> 3, g = (slot & 7) * 8;
            float4 f0 = apre[2 * it], f1 = apre[2 * it + 1];
            u16 th[8] = {f2h(f0.x), f2h(f0.y), f2h(f0.z), f2h(f0.w),
                         f2h(f1.x), f2h(f1.y), f2h(f1.z), f2h(f1.w)};
            *(u16x8*)&Ah[r][g] = *(u16x8*)th;
        }
#pragma unroll
        for (int it = 0; it < 2; ++it) {
            int slot = tid + it * 256, r = slot >> 3, g = (slot & 7) * 8;
            *(u16x8*)&B1[r][g] = b1p[it];
            if (isKV) *(u16x8*)&B2[r][g] = b2p[it];
        }
    };

    f32x4 acc1[2][4] = {}, acc2[2][4] = {};

    load_ab(0);
    write_ab();
    __syncthreads();
    load_ab(64);   // in flight during first compute

    for (int k0 = 0; k0 < F_; k0 += 64) {
#pragma unroll
        for (int ks = 0; ks < 2; ++ks) {
            f16x8 af[2];
#pragma unroll
            for (int mf = 0; mf < 2; ++mf)
                af[mf] = *(const f16x8*)&Ah[w * 32 + mf * 16 + lx][ks * 32 + quad * 8];
#pragma unroll
            for (int nt = 0; nt < 4; ++nt) {
                f16x8 b1 = *(const f16x8*)&B1[nt * 16 + lx][ks * 32 + quad * 8];
#pragma unroll
                for (int mf = 0; mf < 2; ++mf)
                    acc1[mf][nt] = __builtin_amdgcn_mfma_f32_16x16x32_f16(af[mf], b1, acc1[mf][nt], 0, 0, 0);
                if (isKV) {
                    f16x8 b2 = *(const f16x8*)&B2[nt * 16 + lx][ks * 32 + quad * 8];
#pragma unroll
                    for (int mf = 0; mf < 2; ++mf)
                        acc2[mf][nt] = __builtin_amdgcn_mfma_f32_16x16x32_f16(af[mf], b2, acc2[mf][nt], 0, 0, 0);
                }
            }
        }
        if (k0 < F_ - 64) {
            __syncthreads();   // loads for k0+64 landed during this compute
            write_ab();
            __syncthreads();
            if (k0 < F_ - 128) load_ab(k0 + 128);  // issued AFTER barriers
        }
    }

    const int h = n0 >> 6;
    const float scl = isKV ? 1.0f : LOG2E;
    u16* C1 = isKV ? Kw : Qw;
#pragma unroll
    for (int mf = 0; mf < 2; ++mf)
#pragma unroll
        for (int nt = 0; nt < 4; ++nt)
#pragma unroll
            for (int i = 0; i < 4; ++i) {
                int m = m0 + w * 32 + mf * 16 + quad * 4 + i;
                int b = m >> 12, l = m & 4095;
                int d = nt * 16 + lx;
                C1[((size_t)(b * H_ + h) * L_ + l) * D_ + d] = f2h(acc1[mf][nt][i] * scl);
            }
    if (isKV) {
        __syncthreads();
#pragma unroll
        for (int mf = 0; mf < 2; ++mf)
#pragma unroll
            for (int nt = 0; nt < 4; ++nt)
#pragma unroll
                for (int i = 0; i < 4; ++i)
                    Ah[w * 32 + mf * 16 + quad * 4 + i][nt * 16 + lx] = f2bf(acc2[mf][nt][i]);
        __syncthreads();
        int d = tid >> 2, seg = (tid & 3) * 32;
        int b = m0 >> 12;
        u16 tmp[32];
#pragma unroll
        for (int j = 0; j < 32; ++j) tmp[j] = Ah[seg + j][d];
        size_t base = ((size_t)(b * H_ + h) * D_ + d) * L_ + (m0 & 4095) + seg;
#pragma unroll
        for (int c = 0; c < 4; ++c)
            *(u16x8*)(Vw + base + c * 8) = *(u16x8*)&tmp[c * 8];
    }
}

// ---------------------------------------------------------------------------
// Out-projection GEMM, 128x64 tile: A fp16 x Wt fp16 -> C fp32.
// ---------------------------------------------------------------------------
__global__ __launch_bounds__(256) void out_gemm(const u16* __restrict__ A16,
                                                const u16* __restrict__ Wt,
                                                float* __restrict__ Cf) {
    __shared__ u16 As[128][72];
    __shared__ u16 Bs[64][72];
    const int tid = threadIdx.x;
    const int w = tid >> 6, lane = tid & 63, lx = lane & 15, quad = lane >> 4;
    const int m0 = blockIdx.y * 128, n0 = blockIdx.x * 64;

    u16x8 a16p[4];
    u16x8 bp[2];

    auto load_ab = [&](int k0) {
#pragma unroll
        for (int it = 0; it < 4; ++it) {
            int slot = tid + it * 256, r = slot >> 3, g = (slot & 7) * 8;
            a16p[it] = *(const u16x8*)(A16 + (size_t)(m0 + r) * F_ + k0 + g);
        }
#pragma unroll
        for (int it = 0; it < 2; ++it) {
            int slot = tid + it * 256, r = slot >> 3, g = (slot & 7) * 8;
            bp[it] = *(const u16x8*)(Wt + (size_t)(n0 + r) * F_ + k0 + g);
        }
    };
    auto write_ab = [&]() {
#pragma unroll
        for (int it = 0; it < 4; ++it) {
            int slot = tid + it * 256, r = slot >> 3, g = (slot & 7) * 8;
            *(u16x8*)&As[r][g] = a16p[it];
        }
#pragma unroll
        for (int it = 0; it < 2; ++it) {
            int slot = tid + it * 256, r = slot >> 3, g = (slot & 7) * 8;
            *(u16x8*)&Bs[r][g] = bp[it];
        }
    };

    f32x4 acc[2][4] = {};

    load_ab(0);
    write_ab();
    __syncthreads();
    load_ab(64);

    for (int k0 = 0; k0 < F_; k0 += 64) {
#pragma unroll
        for (int ks = 0; ks < 2; ++ks) {
            f16x8 af[2];
#pragma unroll
            for (int mf = 0; mf < 2; ++mf)
                af[mf] = *(const f16x8*)&As[w * 32 + mf * 16 + lx][ks * 32 + quad * 8];
#pragma unroll
            for (int nt = 0; nt < 4; ++nt) {
                f16x8 bf = *(const f16x8*)&Bs[nt * 16 + lx][ks * 32 + quad * 8];
#pragma unroll
                for (int mf = 0; mf < 2; ++mf)
                    acc[mf][nt] = __builtin_amdgcn_mfma_f32_16x16x32_f16(af[mf], bf, acc[mf][nt], 0, 0, 0);
            }
        }
        if (k0 < F_ - 64) {
            __syncthreads();
            write_ab();
            __syncthreads();
            if (k0 < F_ - 128) load_ab(k0 + 128);
        }
    }

#pragma unroll
    for (int mf = 0; mf < 2; ++mf)
#pragma unroll
        for (int nt = 0; nt < 4; ++nt)
#pragma unroll
            for (int i = 0; i < 4; ++i) {
                int m = m0 + w * 32 + mf * 16 + quad * 4 + i;
                int n = n0 + nt * 16 + lx;
                Cf[(size_t)m * F_ + n] = acc[mf][nt][i];
            }
}

// ---------------------------------------------------------------------------
// MFMA flash attention, R2: BQ=256 (4 waves x 64q, qf=4), split-K x2.
// Why qf=4: R1 counters showed the kernel LDS-throughput-bound at CU level
// (~10240 b128 LDS instrs/CU ~= 150k of 228k cycles). Each K/V fragment
// read now feeds 4 MFMAs instead of 2 -> per-CU LDS instrs halve, and
// global K/V fetch halves (512 blocks instead of 1024).
// Register control: each kt is processed as two half-tiles (k-rows 0..31,
// then 32..63): QK -> softmax -> PV per half, so only sv[2][4] (32 acc)
// is live at once on top of o[4][4]+osum[4].
// LDS: true double-buffer (Ks/Vs x2), ONE barrier per kt. Writing buf^1
// mid-iter is safe: the previous iteration's end barrier retired all
// reads of buf^1. P stays fully in-register (permlane32+16 swap trick).
// Occupancy: 2 blocks/CU (512 blocks), launch_bounds(256,2) for 256 VGPR.
// XCD swizzle: (x&7) -> 2 heads per XCD (K/V WS 1 MB < 4 MB L2/XCD).
// ---------------------------------------------------------------------------
__global__ __launch_bounds__(256, 2) void flash_mfma(
    const u16* __restrict__ Qg, const u16* __restrict__ Kg,
    const u16* __restrict__ Vtg, u16* __restrict__ On, float* __restrict__ Ls) {
    __shared__ u16 Ks[2][64][72];   // fp16, double-buffered
    __shared__ u16 Vs[2][64][72];   // bf16, V^T tile [d][kcol], double-buffered

    const int tid = threadIdx.x;
    const int w = tid >> 6, lane = tid & 63, lx = lane & 15, quad = lane >> 4;

    // decode: 512 = 8 xcd * (2 head * 2 split * 16 qtile)
    const int x = blockIdx.x;
    const int t = x >> 3;
    const int hh = t >> 5;
    const int s = (t >> 4) & 1;
    const int bh = (x & 7) * 2 + hh;
    const int q0 = (t & 15) * 256;

    const u16* Qp = Qg + ((size_t)bh * L_ + q0) * D_;
    const u16* Kp = Kg + (size_t)bh * L_ * D_ + (size_t)(s * KHALF) * D_;
    const u16* Vp = Vtg + (size_t)bh * D_ * L_ + s * KHALF;

    // Q fragments straight to registers (B-operand layout), 64 q-rows/wave
    f16x8 qreg[4][2];
#pragma unroll
    for (int qf = 0; qf < 4; ++qf)
#pragma unroll
        for (int ks = 0; ks < 2; ++ks)
            qreg[qf][ks] = *(const f16x8*)(Qp + (size_t)(w * 64 + qf * 16 + lx) * D_ +
                                           ks * 32 + quad * 8);

    u16x8 kp[2], vp[2];
    auto load_kv = [&](int kt) {
#pragma unroll
        for (int it = 0; it < 2; ++it) {
            int slot = tid + it * 256, r = slot >> 3, g = (slot & 7) * 8;
            kp[it] = *(const u16x8*)(Kp + (size_t)(kt * 64 + r) * D_ + g);
            vp[it] = *(const u16x8*)(Vp + (size_t)r * L_ + kt * 64 + g);
        }
    };
    auto write_kv = [&](int p) {
#pragma unroll
        for (int it = 0; it < 2; ++it) {
            int slot = tid + it * 256, r = slot >> 3, g = (slot & 7) * 8;
            *(u16x8*)&Ks[p][r][g] = kp[it];
            *(u16x8*)&Vs[p][r][g] = vp[it];
        }
    };

    const bf16x8 vone = {0x3F80, 0x3F80, 0x3F80, 0x3F80,
                         0x3F80, 0x3F80, 0x3F80, 0x3F80};  // bf16 1.0 x8
    f32x4 o[4][4] = {};
    f32x4 osum[4] = {};

    load_kv(0);
    write_kv(0);
    __syncthreads();
    load_kv(1);   // in flight during first compute

    const int NT = KHALF / 64;
    for (int kt = 0; kt < NT; ++kt) {
        const int p = kt & 1;

        // ---- half-tile A: k-rows 0..31 (nt 0,1) --------------------------
        // S^T = K Q^T : lane holds S^T[k=nt*16+quad*4+i][q=w*64+qf*16+lx]
        f32x4 sv[2][4] = {};
#pragma unroll
        for (int ks = 0; ks < 2; ++ks)
#pragma unroll
            for (int nt = 0; nt < 2; ++nt) {
                f16x8 ak = *(const f16x8*)&Ks[p][nt * 16 + lx][ks * 32 + quad * 8];
#pragma unroll
                for (int qf = 0; qf < 4; ++qf)
                    sv[nt][qf] = __builtin_amdgcn_mfma_f32_16x16x32_f16(ak, qreg[qf][ks], sv[nt][qf], 0, 0, 0);
            }

        // stage next tile into the other buffer (regs loaded last iter;
        // safe: all reads of buf p^1 retired before last iter's barrier)
        if (kt < NT - 1) write_kv(p ^ 1);

        // p = exp2(s); pack to bf16; cross-quad redistribute via
        // permlane32_swap + permlane16_swap (VALU, no LDS round-trip)
        bf16x8 ap0[4];
#pragma unroll
        for (int qf = 0; qf < 4; ++qf) {
            u32 pu[2], pw[2];
#pragma unroll
            for (int nt = 0; nt < 2; ++nt) {
                u32 ub[4];
#pragma unroll
                for (int i = 0; i < 4; ++i)
                    ub[i] = __float_as_uint(__builtin_amdgcn_exp2f(sv[nt][qf][i]));
                pu[nt] = __builtin_amdgcn_perm(ub[1], ub[0], 0x07060302u);
                pw[nt] = __builtin_amdgcn_perm(ub[3], ub[2], 0x07060302u);
            }
            u32x2 r  = __builtin_amdgcn_permlane32_swap(pu[0], pu[1], false, false);
            u32x2 r2 = __builtin_amdgcn_permlane16_swap(r[0], r[1], false, false);
            u32x2 tt = __builtin_amdgcn_permlane32_swap(pw[0], pw[1], false, false);
            u32x2 t2 = __builtin_amdgcn_permlane16_swap(tt[0], tt[1], false, false);
            union { u32 d[4]; bf16x8 h; } cvt;
            cvt.d[0] = r2[0];
            cvt.d[1] = t2[0];
            cvt.d[2] = r2[1];
            cvt.d[3] = t2[1];
            ap0[qf] = cvt.h;
        }

        // PV ks=0 (k 0..31) + row sums
        __builtin_amdgcn_s_setprio(1);
#pragma unroll
        for (int qf = 0; qf < 4; ++qf)
            osum[qf] = __builtin_amdgcn_mfma_f32_16x16x32_bf16(ap0[qf], vone, osum[qf], 0, 0, 0);
#pragma unroll
        for (int nt = 0; nt < 4; ++nt) {
            bf16x8 bv = *(const bf16x8*)&Vs[p][nt * 16 + lx][quad * 8];
#pragma unroll
            for (int qf = 0; qf < 4; ++qf)
                o[qf][nt] = __builtin_amdgcn_mfma_f32_16x16x32_bf16(ap0[qf], bv, o[qf][nt], 0, 0, 0);
        }
        __builtin_amdgcn_s_setprio(0);

        // ---- half-tile B: k-rows 32..63 (nt 2,3) -------------------------
#pragma unroll
        for (int nt = 0; nt < 2; ++nt)
#pragma unroll
            for (int qf = 0; qf < 4; ++qf)
                sv[nt][qf] = (f32x4){0.f, 0.f, 0.f, 0.f};
#pragma unroll
        for (int ks = 0; ks < 2; ++ks)
#pragma unroll
            for (int nt = 0; nt < 2; ++nt) {
                f16x8 ak = *(const f16x8*)&Ks[p][(nt + 2) * 16 + lx][ks * 32 + quad * 8];
#pragma unroll
                for (int qf = 0; qf < 4; ++qf)
                    sv[nt][qf] = __builtin_amdgcn_mfma_f32_16x16x32_f16(ak, qreg[qf][ks], sv[nt][qf], 0, 0, 0);
            }

        bf16x8 ap1[4];
#pragma unroll
        for (int qf = 0; qf < 4; ++qf) {
            u32 pu[2], pw[2];
#pragma unroll
            for (int nt = 0; nt < 2; ++nt) {
                u32 ub[4];
#pragma unroll
                for (int i = 0; i < 4; ++i)
                    ub[i] = __float_as_uint(__builtin_amdgcn_exp2f(sv[nt][qf][i]));
                pu[nt] = __builtin_amdgcn_perm(ub[1], ub[0], 0x07060302u);
                pw[nt] = __builtin_amdgcn_perm(ub[3], ub[2], 0x07060302u);
            }
            u32x2 r  = __builtin_amdgcn_permlane32_swap(pu[0], pu[1], false, false);
            u32x2 r2 = __builtin_amdgcn_permlane16_swap(r[0], r[1], false, false);
            u32x2 tt = __builtin_amdgcn_permlane32_swap(pw[0], pw[1], false, false);
            u32x2 t2 = __builtin_amdgcn_permlane16_swap(tt[0], tt[1], false, false);
            union { u32 d[4]; bf16x8 h; } cvt;
            cvt.d[0] = r2[0];
            cvt.d[1] = t2[0];
            cvt.d[2] = r2[1];
            cvt.d[3] = t2[1];
            ap1[qf] = cvt.h;
        }

        // PV ks=1 (k 32..63) + row sums
        __builtin_amdgcn_s_setprio(1);
#pragma unroll
        for (int qf = 0; qf < 4; ++qf)
            osum[qf] = __builtin_amdgcn_mfma_f32_16x16x32_bf16(ap1[qf], vone, osum[qf], 0, 0, 0);
#pragma unroll
        for (int nt = 0; nt < 4; ++nt) {
            bf16x8 bv = *(const bf16x8*)&Vs[p][nt * 16 + lx][32 + quad * 8];
#pragma unroll
            for (int qf = 0; qf < 4; ++qf)
                o[qf][nt] = __builtin_amdgcn_mfma_f32_16x16x32_bf16(ap1[qf], bv, o[qf][nt], 0, 0, 0);
        }
        __builtin_amdgcn_s_setprio(0);

        if (kt < NT - 2) load_kv(kt + 2);  // next-next tile into regs
        if (kt < NT - 1) __syncthreads();  // ONE barrier per kt (dbuf)
    }

    // write On = O/l (fp16, [B,L,H*D]) and l (f32)
    const int b = bh >> 3, h = bh & 7;
    u16* Op = On + (size_t)s * M_ * F_;
#pragma unroll
    for (int qf = 0; qf < 4; ++qf) {
        float linv[4];
#pragma unroll
        for (int i = 0; i < 4; ++i) linv[i] = 1.f / osum[qf][i];
#pragma unroll
        for (int nt = 0; nt < 4; ++nt)
#pragma unroll
            for (int i = 0; i < 4; ++i) {
                int l = q0 + w * 64 + qf * 16 + quad * 4 + i;
                Op[((size_t)b * L_ + l) * (H_ * D_) + h * D_ + nt * 16 + lx] =
                    f2h(o[qf][nt][i] * linv[i]);
            }
        if (lx == 0) {
            float* lp = Ls + ((size_t)s * (B_ * H_) + bh) * L_ +
                        q0 + w * 64 + qf * 16 + quad * 4;
#pragma unroll
            for (int i = 0; i < 4; ++i) lp[i] = osum[qf][i];
        }
    }
}

// ---------------------------------------------------------------------------
// Combine split-K partials: O = (l1*O1n + l2*O2n) / (l1+l2).
// ---------------------------------------------------------------------------
__global__ __launch_bounds__(256) void reduce_kernel(
    const u16* __restrict__ On, const float* __restrict__ Ls,
    u16* __restrict__ Ow) {
    int gid = blockIdx.x * 256 + threadIdx.x;  // u16x8 group, grid covers M_*F_/8
    size_t off = (size_t)gid * 8;
    int row = gid >> 3;                        // 64 elems per (b,l,h) row
    int b = row >> 15, rem = row & 32767;
    int l = rem >> 3, h = rem & 7;
    int lidx = ((b * H_ + h) << 12) + l;
    float l1 = Ls[lidx], l2 = Ls[B_ * H_ * L_ + lidx];
    float w1 = l1 / (l1 + l2), w2 = 1.f - w1;
    u16x8 a = *(const u16x8*)(On + off);
    u16x8 c = *(const u16x8*)(On + (size_t)M_ * F_ + off);
    u16 r[8];
#pragma unroll
    for (int j = 0; j < 8; ++j)
        r[j] = f2h(w1 * h2f(a[j]) + w2 * h2f(c[j]));
    *(u16x8*)(Ow + off) = *(u16x8*)r;
}

// ---------------------------------------------------------------------------
extern "C" void kernel_launch(void* const* d_in, const int* in_sizes, int n_in,
                              void* d_out, int out_size, void* d_ws, size_t ws_size,
                              hipStream_t stream)
{
    const float* Xq  = (const float*)d_in[0];
    const float* Xkv = (const float*)d_in[1];
    const float* Wq  = (const float*)d_in[2];
    const float* Wk  = (const float*)d_in[3];
    const float* Wv  = (const float*)d_in[4];
    const float* Wo  = (const float*)d_in[5];
    float* out = (float*)d_out;

    u16* ws  = (u16*)d_ws;
    const size_t MF = (size_t)M_ * F_;
    const size_t FF = (size_t)F_ * F_;
    u16* Wqt = ws;             // W^T 512x512 fp16 each
    u16* Wkt = Wqt + FF;
    u16* Wvt = Wkt + FF;
    u16* Wot = Wvt + FF;
    u16* Qw  = Wot + FF;       // [B,H,L,D] fp16, pre-scaled by log2e
    u16* Kw  = Qw + MF;        // [B,H,L,D] fp16
    u16* Vw  = Kw + MF;        // [B,H,D,L] bf16
    u16* On  = Vw + MF;        // 2 x [B,L,H*D] fp16 split partials
    float* Ls = (float*)(On + 2 * MF);  // 2 x [BH, L] f32
    u16* Ow  = Qw;             // reduced O aliases Qw (dead after flash)

    wt_kernel<<<dim3(16, 16, 4), 256, 0, stream>>>(Wq, Wk, Wv, Wo,
                                                   Wqt, Wkt, Wvt, Wot);

    proj_kernel<<<dim3(8, 64, 2), 256, 0, stream>>>(Xq, Xkv, Wqt, Wkt, Wvt,
                                                    Qw, Kw, Vw);

    flash_mfma<<<dim3(512), 256, 0, stream>>>(Qw, Kw, Vw, On, Ls);

    reduce_kernel<<<dim3((int)(MF / 8 / 256)), 256, 0, stream>>>(On, Ls, Ow);

    out_gemm<<<dim3(8, 64), 256, 0, stream>>>(Ow, Wot, out);
}